// Round 1
// 301.169 us; speedup vs baseline: 1.0955x; 1.0955x over previous
//
#include <hip/hip_runtime.h>

// MaskedConv2D bf16-MFMA implicit GEMM, v4. B=8, CIN=COUT=64, H=W=256, K=3, PAD=1.
// GEMM view: M=64 (co), K=576 (ci*9 taps), N=pixels.
// Block: 512 thr = 8 waves; tile = 64 co x (4 rows x 64 cols).
// Wave v: output row (v&3), col-half (v>>2) -> wave tile 64co x 32px, acc 4x2 frags.
// mfma_f32_16x16x32_bf16: A[m=lane&15][k=(lane>>4)*8+j], C/D: col=lane&15, row=(lane>>4)*4+reg.
//
// v4 change vs v3 (theory: latency-bound staging): staging is now
// issue-all-56-loads-then-consume (branchless clamped addresses, single pipelined
// vmcnt drain) instead of 7 rounds of {8 loads -> vmcnt(0) -> ds_write}.
// Validity mask loads hoisted before __syncthreads (overlap barrier);
// bias + ds_bpermute hoisted before K loop (epilogue = pure stores).

#define B_    8
#define C_    64
#define H_    256
#define W_    256
#define HW_   (H_ * W_)

typedef __attribute__((ext_vector_type(8))) short bf16x8;
typedef __attribute__((ext_vector_type(4))) float f32x4;

__device__ __forceinline__ unsigned short f2bf(float f) {
    unsigned int u = __float_as_uint(f);
    u = (u + 0x7FFFu + ((u >> 16) & 1u)) >> 16;   // RNE
    return (unsigned short)u;
}

// ---- weight conversion: fp32 [co][ci][3][3] -> bf16 A-fragment blob ----
// frag f = s*4 + mf  (s = tap*2 + kblk); lane l holds 8 bf16 at (f*64+l)*16 B:
//   co = mf*16 + (l&15); ci = kblk*32 + (l>>4)*8 + j
__global__ __launch_bounds__(256) void wconv(const float* __restrict__ wgt,
                                             unsigned short* __restrict__ wsA)
{
    const int gid  = blockIdx.x * 256 + threadIdx.x;   // 18*256 = 4608
    const int s    = gid >> 8;
    const int rest = gid & 255;
    const int mf   = rest >> 6;
    const int lane = rest & 63;
    const int tap  = s >> 1;
    const int kblk = s & 1;
    const int kh = tap / 3, kw = tap % 3;
    const int co = mf * 16 + (lane & 15);
    unsigned short v[8];
#pragma unroll
    for (int j = 0; j < 8; ++j) {
        const int ci = kblk * 32 + (lane >> 4) * 8 + j;
        v[j] = f2bf(wgt[((co * C_ + ci) * 3 + kh) * 3 + kw]);
    }
    unsigned short* dst = wsA + (size_t)gid * 8;
    *(uint4*)dst = *(const uint4*)v;
}

// ---- main kernel ----
#define TROWS 6          // 4 + 2 halo
#define TCOLS 66         // 64 + 2 halo
#define CELLP 72         // padded ci stride in shorts (144 B; b128 reads/writes uniform)
#define NU    (TROWS * TCOLS * 8)   // 3168 staging units
#define NCHUNK 7                    // ceil(3168/512)

__global__ __launch_bounds__(512, 4) void masked_conv_mfma(
    const float* __restrict__ x,
    const float* __restrict__ mask,
    const unsigned short* __restrict__ wsA,
    const float* __restrict__ bias,
    float* __restrict__ out)
{
    __shared__ unsigned short xs[TROWS * TCOLS * CELLP];  // 57024 B

    const int tid  = threadIdx.x;
    const int wave = tid >> 6;
    const int lane = tid & 63;
    const int l15  = lane & 15;
    const int lq   = lane >> 4;

    const int w0 = blockIdx.x * 64;
    const int h0 = blockIdx.y * 4;
    const int b  = blockIdx.z;

    const float* xb = x + (size_t)b * C_ * HW_;

    // ---- stage x tile: [6 rows][66 cols][64 ci] bf16 ----
    // Work unit = (row, ci-octet, col): 8 strided global dwords -> 1 ds_write_b128.
    // Phase A: issue ALL loads (up to 56/thread) with branchless clamped
    // addresses so they pipeline as one long vmem burst (no per-unit vmcnt(0)).
    float va[NCHUNK][8];
    int   cell[NCHUNK];
    int   okf[NCHUNK];
#pragma unroll
    for (int k = 0; k < NCHUNK; ++k) {
        const int u0 = tid + (k << 9);
        const int u  = (u0 < NU) ? u0 : 0;        // clamp: dup unit 0, write guarded
        const int col = u % TCOLS;
        const int t2  = u / TCOLS;
        const int oct = t2 & 7;
        const int row = t2 >> 3;
        const int gh = h0 - 1 + row;
        const int gw = w0 - 1 + col;
        const int ok = (gh >= 0) & (gh < H_) & (gw >= 0) & (gw < W_);
        const float* px = xb + ((size_t)(oct * 8) * H_ + (ok ? gh : 0)) * W_
                             + (ok ? gw : 0);
#pragma unroll
        for (int j = 0; j < 8; ++j) va[k][j] = px[(size_t)j * HW_];
        cell[k] = (row * TCOLS + col) * CELLP + oct * 8;
        okf[k]  = ok;
    }
    // Phase B: convert + LDS write (partial vmcnt waits, stays pipelined)
#pragma unroll
    for (int k = 0; k < NCHUNK; ++k) {
        if (k == NCHUNK - 1 && tid >= (NU - (NCHUNK - 1) * 512)) continue; // tid>=96
        unsigned short v[8];
#pragma unroll
        for (int j = 0; j < 8; ++j)
            v[j] = okf[k] ? f2bf(va[k][j]) : (unsigned short)0;
        *(uint4*)&xs[cell[k]] = *(const uint4*)v;
    }

    // ---- validity: issued BEFORE the barrier so the 9 mask loads overlap it.
    // Lanes 0..31 cover the wave's 32 px (lanes 32..63 duplicate). Branchless.
    const int hrow = wave & 3;        // output row within tile
    const int nh   = wave >> 2;       // col half (0/1)
    const int h    = h0 + hrow;
    const int pcol = w0 + nh * 32 + (lane & 31);
    int valid = 0;
    {
        const float* mb = mask + (size_t)b * HW_;
#pragma unroll
        for (int dh = -1; dh <= 1; ++dh) {
#pragma unroll
            for (int dw = -1; dw <= 1; ++dw) {
                const int hh = h + dh;
                const int ww = pcol + dw;
                const int ok = (hh >= 0) & (hh < H_) & (ww >= 0) & (ww < W_);
                const float mv = mb[ok ? (hh * W_ + ww) : 0];
                valid |= ok & (mv != 0.0f ? 1 : 0);
            }
        }
    }

    __syncthreads();

    // ---- hoist epilogue latency: bias frags + validity bpermutes ----
    float bv[4][4];
#pragma unroll
    for (int mf = 0; mf < 4; ++mf)
#pragma unroll
        for (int reg = 0; reg < 4; ++reg)
            bv[mf][reg] = bias[mf * 16 + lq * 4 + reg];
    const int vn0 = __builtin_amdgcn_ds_bpermute(l15 << 2, valid);
    const int vn1 = __builtin_amdgcn_ds_bpermute((16 + l15) << 2, valid);

    // ---- K loop: 9 taps x 2 ci-halves, no barriers ----
    f32x4 acc[4][2];
#pragma unroll
    for (int mf = 0; mf < 4; ++mf)
#pragma unroll
        for (int nf = 0; nf < 2; ++nf)
            acc[mf][nf] = (f32x4){0.f, 0.f, 0.f, 0.f};

    const bf16x8* wA = (const bf16x8*)wsA;

#pragma unroll 1
    for (int kh = 0; kh < 3; ++kh) {
        const int rowbase = (hrow + kh) * TCOLS + nh * 32;
#pragma unroll
        for (int kw = 0; kw < 3; ++kw) {
#pragma unroll
            for (int kblk = 0; kblk < 2; ++kblk) {
                const int s = (kh * 3 + kw) * 2 + kblk;
                bf16x8 a[4];
#pragma unroll
                for (int mf = 0; mf < 4; ++mf)
                    a[mf] = wA[(s * 4 + mf) * 64 + lane];
                bf16x8 bf[2];
#pragma unroll
                for (int nf = 0; nf < 2; ++nf) {
                    const int cell2 = rowbase + nf * 16 + l15 + kw;
                    bf[nf] = *(const bf16x8*)&xs[cell2 * CELLP + kblk * 32 + lq * 8];
                }
#pragma unroll
                for (int mf = 0; mf < 4; ++mf)
#pragma unroll
                    for (int nf = 0; nf < 2; ++nf)
                        acc[mf][nf] = __builtin_amdgcn_mfma_f32_16x16x32_bf16(
                            a[mf], bf[nf], acc[mf][nf], 0, 0, 0);
            }
        }
    }

    // ---- epilogue: pure stores ----
#pragma unroll
    for (int nf = 0; nf < 2; ++nf) {
        const int cloc = nf * 16 + l15;                       // 0..31 within half
        const int vn = nf ? vn1 : vn0;
        float* ob = out + ((size_t)(b * C_) * H_ + h) * W_ + w0 + nh * 32 + cloc;
#pragma unroll
        for (int mf = 0; mf < 4; ++mf) {
#pragma unroll
            for (int reg = 0; reg < 4; ++reg) {
                const float val = vn ? (acc[mf][nf][reg] + bv[mf][reg]) : 0.0f;
                ob[(size_t)(mf * 16 + lq * 4 + reg) * HW_] = val;
            }
        }
    }
}

extern "C" void kernel_launch(void* const* d_in, const int* in_sizes, int n_in,
                              void* d_out, int out_size, void* d_ws, size_t ws_size,
                              hipStream_t stream) {
    const float* x    = (const float*)d_in[0];
    const float* mask = (const float*)d_in[1];
    const float* wgt  = (const float*)d_in[2];
    const float* bias = (const float*)d_in[3];
    float* out        = (float*)d_out;
    unsigned short* wsA = (unsigned short*)d_ws;   // 73728 B used

    wconv<<<18, 256, 0, stream>>>(wgt, wsA);

    dim3 grid(W_ / 64, H_ / 4, B_);
    masked_conv_mfma<<<grid, 512, 0, stream>>>(x, mask, wsA, bias, out);
}